// Round 2
// baseline (177.029 us; speedup 1.0000x reference)
//
#include <hip/hip_runtime.h>

// BahdanauAttention_16518444220431 — diagonal-DP recurrence on MI355X (gfx950).
// R12 = R11 + SELF-KS FROM REGISTERS (dual-zk): the wave's packed zk is
// bit-identical to the B-fragments for ks in [4w,4w+3] (lane l holds
// U[row=lane31+32mt][chunk=(ot0+t2)*4+2p+khalf] = ds_read of chunk 2ks+khalf
// at ks=4w+2t2+p). Those 16 of 64 MFMAs run with ZERO LDS dependency and are
// front-loaded to cover the interval-top write+read warmup. GEMM(h) needs
// state(h-2) so BOTH phases' zk stay live (zkU/zkD, +32 regs); paid for by
// NC 14->10 with afs streamed in 3 batches of 2 slots (>=4-ks lead, R10
// lesson). ks-ROTATION keeps reg indices compile-time: w2c slot i = ks
// (4w+i)&15; runtime ks only in addresses. LDS reads/CU/interval 256->192.
// Theory: wall = MFMA pipe (4.4k cyc, 47%) serialized with LDS pipe (4.0k,
// 44%) because every ks's MFMAs chain on just-issued ds_reads; R11 proved
// conflicts+setprio are not the path. REGISTER LEDGER (cap 256 @ 2w/SIMD):
// acc 64 AGPR + w2c[2][10]=80 + zk 64 + w1x 8 + afs-peak ~16 + working ~25
// = ~257 -> watch FETCH>10MB spill tripwire. LESSONS: launch_bounds (256,2)
// (tighter spills acc, R2/R3); 128-AGPR acc + streamed A spills (R9).

typedef __bf16 bf16x8 __attribute__((ext_vector_type(8)));
typedef __bf16 bf16x4 __attribute__((ext_vector_type(4)));
typedef float f32x16 __attribute__((ext_vector_type(16)));
typedef unsigned int uint2v __attribute__((ext_vector_type(2)));

#define MFMA32(a, b, c) __builtin_amdgcn_mfma_f32_32x32x16_bf16(a, b, c, 0, 0, 0)

__device__ __forceinline__ unsigned short f2bf(float f) {
  unsigned int u = __builtin_bit_cast(unsigned int, f);
  u += 0x7fffu + ((u >> 16) & 1u);
  return (unsigned short)(u >> 16);
}

// ws layout (bf16 elements):
//   [0,65536)        W2 fragments: ((ot*16+ks)*64+lane)*8+j ; o=ot*32+(lane&31), k=ks*16+(lane>>5)*8+j
//   [65536,131072)   W4 fragments, same permutation
//   [131072,135168)  W1-extra frags: lanes<32: j<4 -> W1[o][j], j==4 -> b1[o]+b2[o], else 0
//   [135168,139264)  W3-extra frags: j==4 -> b3[o]+2*b4[o]
__global__ void prep_kernel(const float* __restrict__ W1, const float* __restrict__ b1,
                            const float* __restrict__ W2, const float* __restrict__ b2,
                            const float* __restrict__ W3, const float* __restrict__ b3,
                            const float* __restrict__ W4, const float* __restrict__ b4,
                            unsigned short* __restrict__ ws) {
  int idx = blockIdx.x * 256 + threadIdx.x;
  if (idx >= 139264) return;
  float v = 0.0f;
  if (idx < 131072) {
    const float* W = (idx < 65536) ? W2 : W4;
    int i = idx & 65535;
    int j = i & 7, f = i >> 3;
    int lane = f & 63, slot = f >> 6;
    int ks = slot & 15, ot = slot >> 4;
    int o = ot * 32 + (lane & 31);
    int k = ks * 16 + (lane >> 5) * 8 + j;
    v = W[o * 256 + k];
  } else {
    int i = idx - 131072;
    bool first = (i < 4096);
    int ii = i & 4095;
    int j = ii & 7, f = ii >> 3;
    int lane = f & 63, ot = f >> 6;
    int o = ot * 32 + (lane & 31);
    if (lane < 32) {
      if (j < 4) v = first ? W1[o * 4 + j] : W3[o * 4 + j];
      else if (j == 4) v = first ? (b1[o] + b2[o]) : (b3[o] + 2.0f * b4[o]);
    }
  }
  ws[idx] = f2bf(v);
}

#define NC 10  // W2 slots cached in regs; slots NC..15 streamed in 3 batches

// Load afs slots S0,S0+1 (physical ks rotated by 4w).
#define LOAD_AFS2(S0) { \
    int ksr_ = (4 * w + NC + (S0)) & 15; \
    afs[S0][0] = __builtin_bit_cast(bf16x8, w2f[(ot0 * 16 + ksr_) * 64 + l]); \
    afs[S0][1] = __builtin_bit_cast(bf16x8, w2f[((ot0 + 1) * 16 + ksr_) * 64 + l]); \
    ksr_ = (4 * w + NC + (S0) + 1) & 15; \
    afs[(S0) + 1][0] = __builtin_bit_cast(bf16x8, w2f[(ot0 * 16 + ksr_) * 64 + l]); \
    afs[(S0) + 1][1] = __builtin_bit_cast(bf16x8, w2f[((ot0 + 1) * 16 + ksr_) * 64 + l]); }

#define PACK(ZS) \
  _Pragma("unroll") for (int mt = 0; mt < 2; ++mt) { \
    _Pragma("unroll") for (int t2 = 0; t2 < 2; ++t2) { \
      unsigned lo[4], hi[4]; \
      _Pragma("unroll") for (int q = 0; q < 4; ++q) { \
        bf16x4 h; \
        h.x = (__bf16)fmaxf(acc[mt][t2][4 * q + 0], 0.0f); \
        h.y = (__bf16)fmaxf(acc[mt][t2][4 * q + 1], 0.0f); \
        h.z = (__bf16)fmaxf(acc[mt][t2][4 * q + 2], 0.0f); \
        h.w = (__bf16)fmaxf(acc[mt][t2][4 * q + 3], 0.0f); \
        uint2 u = __builtin_bit_cast(uint2, h); \
        lo[q] = u.x; hi[q] = u.y; \
      } \
      uint2v r0 = __builtin_amdgcn_permlane32_swap(lo[0], lo[1], false, false); \
      uint2v r1 = __builtin_amdgcn_permlane32_swap(hi[0], hi[1], false, false); \
      ZS[mt][t2][0] = make_int4((int)r0.x, (int)r1.x, (int)r0.y, (int)r1.y); \
      uint2v r2 = __builtin_amdgcn_permlane32_swap(lo[2], lo[3], false, false); \
      uint2v r3 = __builtin_amdgcn_permlane32_swap(hi[2], hi[3], false, false); \
      ZS[mt][t2][1] = make_int4((int)r2.x, (int)r3.x, (int)r2.y, (int)r3.y); \
    } \
  }

// One DP interval at phase PH (compile-time 0/1), DP step T (runtime).
// ZS = this phase's zk (self B-frags, state T-1 of same phase; repacked at end).
// ZO = other phase's zk (written to LDS at top).
#define INTERVAL(PH, T, ZS, ZO, DOW, DOG) { \
  bf16x8 afs[16 - NC][2]; \
  if (DOG) LOAD_AFS2(0) \
  f32x16 acc[2][2] = {}; \
  if (DOW) { \
    int4* Uw = U[(PH) ^ 1]; \
    _Pragma("unroll") for (int mt = 0; mt < 2; ++mt) \
    _Pragma("unroll") for (int t2 = 0; t2 < 2; ++t2) \
    _Pragma("unroll") for (int p = 0; p < 2; ++p) \
      Uw[((ot0 + t2) * 4 + 2 * p + khalf) * 64 + mt * 32 + lane31] = ZO[mt][t2][p]; \
  } \
  __builtin_amdgcn_s_setprio(1); \
  _Pragma("unroll") for (int mt = 0; mt < 2; ++mt) { \
    int m = mt ? mrow1 : mrow0; \
    int widx = (PH) == 0 ? (m + (T) - 1) : (m + 17 - (T)); \
    const int4* p = (l < 32) ? (xw + widx) : (&zc); \
    bf16x8 bx = __builtin_bit_cast(bf16x8, *p); \
    acc[mt][0] = MFMA32(w1x[0], bx, acc[mt][0]); \
    acc[mt][1] = MFMA32(w1x[1], bx, acc[mt][1]); \
  } \
  if (DOG) { \
    _Pragma("unroll") for (int s = 0; s < 4; ++s) { \
      bf16x8 bu0 = __builtin_bit_cast(bf16x8, ZS[0][s >> 1][s & 1]); \
      bf16x8 bu1 = __builtin_bit_cast(bf16x8, ZS[1][s >> 1][s & 1]); \
      acc[0][0] = MFMA32(w2c[0][s], bu0, acc[0][0]); \
      acc[0][1] = MFMA32(w2c[1][s], bu0, acc[0][1]); \
      acc[1][0] = MFMA32(w2c[0][s], bu1, acc[1][0]); \
      acc[1][1] = MFMA32(w2c[1][s], bu1, acc[1][1]); \
    } \
    LOAD_AFS2(2) \
    const int4* Ur = U[PH]; \
    _Pragma("unroll") for (int i = 4; i < 16; ++i) { \
      if (i == 8) LOAD_AFS2(4) \
      int ksr = (4 * w + i) & 15; \
      int c0 = 2 * ksr + khalf; \
      bf16x8 bu0 = __builtin_bit_cast(bf16x8, Ur[c0 * 64 + mrow0]); \
      bf16x8 bu1 = __builtin_bit_cast(bf16x8, Ur[c0 * 64 + mrow1]); \
      bf16x8 af0 = (i < NC) ? w2c[0][i] : afs[i - NC][0]; \
      bf16x8 af1 = (i < NC) ? w2c[1][i] : afs[i - NC][1]; \
      acc[0][0] = MFMA32(af0, bu0, acc[0][0]); \
      acc[0][1] = MFMA32(af1, bu0, acc[0][1]); \
      acc[1][0] = MFMA32(af0, bu1, acc[1][0]); \
      acc[1][1] = MFMA32(af1, bu1, acc[1][1]); \
    } \
  } \
  __builtin_amdgcn_s_setprio(0); \
  PACK(ZS) \
  __syncthreads(); \
}

// Final-GEMM phase: self slots from ZS regs, rest from LDS, A from w4f (L2).
#define FINAL_PH(PH, ZS) { \
  const int4* Sp = U[PH]; \
  _Pragma("unroll") for (int s = 0; s < 4; ++s) { \
    int ksr = 4 * w + s; \
    bf16x8 af0 = __builtin_bit_cast(bf16x8, w4f[(ot0 * 16 + ksr) * 64 + l]); \
    bf16x8 af1 = __builtin_bit_cast(bf16x8, w4f[((ot0 + 1) * 16 + ksr) * 64 + l]); \
    bf16x8 bu0 = __builtin_bit_cast(bf16x8, ZS[0][s >> 1][s & 1]); \
    bf16x8 bu1 = __builtin_bit_cast(bf16x8, ZS[1][s >> 1][s & 1]); \
    acc[0][0] = MFMA32(af0, bu0, acc[0][0]); \
    acc[0][1] = MFMA32(af1, bu0, acc[0][1]); \
    acc[1][0] = MFMA32(af0, bu1, acc[1][0]); \
    acc[1][1] = MFMA32(af1, bu1, acc[1][1]); \
  } \
  _Pragma("unroll") for (int i = 4; i < 16; ++i) { \
    int ksr = (4 * w + i) & 15; \
    int c0 = 2 * ksr + khalf; \
    bf16x8 bu0 = __builtin_bit_cast(bf16x8, Sp[c0 * 64 + mrow0]); \
    bf16x8 bu1 = __builtin_bit_cast(bf16x8, Sp[c0 * 64 + mrow1]); \
    bf16x8 af0 = __builtin_bit_cast(bf16x8, w4f[(ot0 * 16 + ksr) * 64 + l]); \
    bf16x8 af1 = __builtin_bit_cast(bf16x8, w4f[((ot0 + 1) * 16 + ksr) * 64 + l]); \
    acc[0][0] = MFMA32(af0, bu0, acc[0][0]); \
    acc[0][1] = MFMA32(af1, bu0, acc[0][1]); \
    acc[1][0] = MFMA32(af0, bu1, acc[1][0]); \
    acc[1][1] = MFMA32(af1, bu1, acc[1][1]); \
  } }

__global__ __launch_bounds__(256, 2)
void chain_kernel(const float* __restrict__ x, const unsigned short* __restrict__ ws,
                  float* __restrict__ out) {
  // U[ph], chunk-major: U[ph][c*64 + r] = bf16 elems [8c..8c+7] of row r.
  __shared__ int4 U[2][32 * 64];
  __shared__ int4 xw[80];   // [x0,x1,x2,x3,1,0,0,0] bf16 chunks, rows j0-8 .. j0+71
  __shared__ int4 zc;

  const int tid = threadIdx.x;
  const int l = tid & 63;
  const int w = tid >> 6;
  const int lane31 = l & 31;
  const int khalf = l >> 5;
  const int tile = blockIdx.x;
  const int b = tile >> 5;
  const int j0 = (tile & 31) * 64;

  const int4* w2f = (const int4*)ws;
  const int4* w4f = (const int4*)(ws + 65536);
  const int4* w1xg = (const int4*)(ws + 131072);
  const int4* w3xg = (const int4*)(ws + 135168);

  if (tid == 0) zc = make_int4(0, 0, 0, 0);
  if (tid < 80) {
    int j = j0 - 8 + tid;
    int4 c = make_int4(0, 0, 0, 0);
    if (j >= 0 && j < 2048) {
      const float* xb = x + (b * 4) * 2048 + j;
      unsigned short h0 = f2bf(xb[0]);
      unsigned short h1 = f2bf(xb[2048]);
      unsigned short h2 = f2bf(xb[4096]);
      unsigned short h3 = f2bf(xb[6144]);
      c = make_int4((int)(h0 | ((unsigned int)h1 << 16)),
                    (int)(h2 | ((unsigned int)h3 << 16)),
                    0x00003f80, 0);  // chunk[4] = bf16(1.0) multiplies the bias row
    }
    xw[tid] = c;
  }

  const int ot0 = w * 2;
  // Rotated W2 cache: slot i holds physical ks = (4w+i)&15, so slots 0..3 are
  // this wave's SELF ks (matching its own zk chunks) at compile-time indices.
  bf16x8 w2c[2][NC];
  bf16x8 w1x[2];
#pragma unroll
  for (int t2 = 0; t2 < 2; ++t2) {
    w1x[t2] = __builtin_bit_cast(bf16x8, w1xg[(ot0 + t2) * 64 + l]);
#pragma unroll
    for (int i = 0; i < NC; ++i) {
      int ksr = (4 * w + i) & 15;
      w2c[t2][i] = __builtin_bit_cast(bf16x8, w2f[((ot0 + t2) * 16 + ksr) * 64 + l]);
    }
  }
  __syncthreads();

  const int mrow0 = lane31;
  const int mrow1 = 32 + lane31;

  // zkU/zkD: packed state per phase, in B-fragment layout. zk[mt][t2][p] =
  // U chunk (ot0+t2)*4+2p+khalf at row mt*32+lane31. Lives 2 intervals:
  // packed at h, LDS-written at h+1, self-consumed (regs) at h+2.
  int4 zkU[2][2][2], zkD[2][2][2];

  // ---- t=1 peel (no previous state, no GEMM) ----
  INTERVAL(0, 1, zkU, zkD, false, false)
  INTERVAL(1, 1, zkD, zkU, true, false)

#pragma unroll 1
  for (int tt = 1; tt < 8; ++tt) {
    INTERVAL(0, tt + 1, zkU, zkD, true, true)
    INTERVAL(1, tt + 1, zkD, zkU, true, true)
  }

  // ---- flush last down-state (zkD = state h=15) -> U1, then final GEMM ----
  {
    int4* Uw = U[1];
#pragma unroll
    for (int mt = 0; mt < 2; ++mt)
#pragma unroll
      for (int t2 = 0; t2 < 2; ++t2)
#pragma unroll
        for (int p = 0; p < 2; ++p)
          Uw[((ot0 + t2) * 4 + 2 * p + khalf) * 64 + mt * 32 + lane31] = zkD[mt][t2][p];
  }
  __syncthreads();

  // ---- final: miu^T = relu(W3x + b3 + 2b4 + W4*U0 + W4*U1), in-block ----
  {
    f32x16 acc[2][2] = {};   // [mt][ot]
    bf16x8 w3x0 = __builtin_bit_cast(bf16x8, w3xg[ot0 * 64 + l]);
    bf16x8 w3x1 = __builtin_bit_cast(bf16x8, w3xg[(ot0 + 1) * 64 + l]);
    __builtin_amdgcn_s_setprio(1);
#pragma unroll
    for (int mt = 0; mt < 2; ++mt) {
      int m = mt ? mrow1 : mrow0;
      const int4* p = (l < 32) ? (xw + m + 8) : (&zc);
      bf16x8 bx = __builtin_bit_cast(bf16x8, *p);
      acc[mt][0] = MFMA32(w3x0, bx, acc[mt][0]);
      acc[mt][1] = MFMA32(w3x1, bx, acc[mt][1]);
    }
    FINAL_PH(0, zkU)
    FINAL_PH(1, zkD)
    __builtin_amdgcn_s_setprio(0);
#pragma unroll
    for (int mt = 0; mt < 2; ++mt) {
      int m = mt ? mrow1 : mrow0;
      int pbase = (b * 2048 + j0 + m) * 256;
#pragma unroll
      for (int t2 = 0; t2 < 2; ++t2) {
#pragma unroll
        for (int q = 0; q < 4; ++q) {
          int ob = (ot0 + t2) * 32 + 8 * q + 4 * khalf;
          float4 v;
          v.x = fmaxf(acc[mt][t2][4 * q + 0], 0.0f);
          v.y = fmaxf(acc[mt][t2][4 * q + 1], 0.0f);
          v.z = fmaxf(acc[mt][t2][4 * q + 2], 0.0f);
          v.w = fmaxf(acc[mt][t2][4 * q + 3], 0.0f);
          *(float4*)(out + pbase + ob) = v;
        }
      }
    }
  }
}

extern "C" void kernel_launch(void* const* d_in, const int* in_sizes, int n_in,
                              void* d_out, int out_size, void* d_ws, size_t ws_size,
                              hipStream_t stream) {
  const float* x  = (const float*)d_in[0];
  const float* W1 = (const float*)d_in[1];
  const float* b1 = (const float*)d_in[2];
  const float* W2 = (const float*)d_in[3];
  const float* b2 = (const float*)d_in[4];
  const float* W3 = (const float*)d_in[5];
  const float* b3 = (const float*)d_in[6];
  const float* W4 = (const float*)d_in[7];
  const float* b4 = (const float*)d_in[8];
  unsigned short* ws = (unsigned short*)d_ws;

  prep_kernel<<<544, 256, 0, stream>>>(W1, b1, W2, b2, W3, b3, W4, b4, ws);
  chain_kernel<<<512, 256, 0, stream>>>(x, ws, (float*)d_out);
}